// Round 5
// baseline (69.171 us; speedup 1.0000x reference)
//
#include <hip/hip_runtime.h>
#include <math.h>

// Problem constants (from reference)
constexpr int kC   = 3;
constexpr int kTIn = 2048;
constexpr int kR   = 64;
constexpr int kTB  = 128;
constexpr float kAlpha = 10.0f;
constexpr float kLog2e = 1.44269504088896f;

constexpr int kLoads = kC * kTIn / 256;   // 24 chunks of 256 floats (1 KB) per sample

#ifndef __has_builtin
#define __has_builtin(x) 0
#endif

static __device__ __forceinline__ float fast_rcp(float x) {
#if __has_builtin(__builtin_amdgcn_rcpf)
    return __builtin_amdgcn_rcpf(x);
#else
    return 1.0f / x;
#endif
}

static __device__ __forceinline__ float fast_exp2(float x) {
#if __has_builtin(__builtin_amdgcn_exp2f)
    return __builtin_amdgcn_exp2f(x);
#else
    return __builtin_exp2f(x);
#endif
}

static __device__ __forceinline__ void sched_fence() {
#if __has_builtin(__builtin_amdgcn_sched_barrier)
    __builtin_amdgcn_sched_barrier(0);
#endif
}

// Issue 24 async global->LDS loads (1 KB each: 64 lanes x 16 B) for sample b.
// LDS dest is wave-uniform base + lane*16 (HW rule); global src is per-lane.
static __device__ __forceinline__
void issue_sample_loads(const float* __restrict__ traces, long long b,
                        float* raw, int lane)
{
    const float* src = traces + b * (long long)(kC * kTIn) + lane * 4;
    #pragma unroll
    for (int j = 0; j < kLoads; ++j) {
        __builtin_amdgcn_global_load_lds(
            (const __attribute__((address_space(1))) void*)(src + j * 256),
            (__attribute__((address_space(3))) void*)(raw + j * 256),
            16, 0, 0);
    }
}

// ---------------------------------------------------------------------------
// Per-resonator transcendental params, once (libm accuracy).
// ws: [4][kR] = freq, decay, thr, thrE (= ALPHA*log2e*thr)
// ---------------------------------------------------------------------------
__global__ void param_kernel(const float* __restrict__ freq_raw,
                             const float* __restrict__ q_raw,
                             const float* __restrict__ thr_raw,
                             float* __restrict__ pp)
{
    const int r = threadIdx.x;
    if (r >= kR) return;
    const float freq  = 0.03f + 0.17f / (1.0f + expf(-freq_raw[r]));
    const float qf    = 1.5f + log1pf(expf(q_raw[r]));
    const float decay = expf(-1.0f / qf);
    const float thr   = 0.35f + 0.75f / (1.0f + expf(-thr_raw[r]));
    pp[0 * kR + r] = freq;
    pp[1 * kR + r] = decay;
    pp[2 * kR + r] = thr;
    pp[3 * kR + r] = thr * (kAlpha * kLog2e);
}

// ---------------------------------------------------------------------------
// One wave per 64-thread block; grid-stride over samples. LDS-staged pipeline:
//   vmcnt(0)  -> pool raw[] (ds_read_b128 + quad shfl) -> lgkmcnt(0)
//   -> issue next sample's global_load_lds (drain under the scan)
//   -> 128-step scan from sp[] -> store.
// No __syncthreads anywhere; 26 KB LDS/block -> 6 blocks/CU.
// ---------------------------------------------------------------------------
__global__ __launch_bounds__(64)
void fused_encoder_kernel(const float* __restrict__ traces,
                          const float* __restrict__ drive_w,
                          const float* __restrict__ drive_b,
                          const float* __restrict__ pp,
                          float* __restrict__ out,
                          int totalB)
{
    __shared__ float raw[kC * kTIn];     // 24 KB: exact copy of one sample
    __shared__ float sp[kTB * 4];        // 2 KB:  [t]{c0,c1,c2,pad}

    const int lane = threadIdx.x;

    // per-lane resonator params (lane == resonator)
    const int r = lane;
    const float w0   = drive_w[r * kC + 0];
    const float w1   = drive_w[r * kC + 1];
    const float w2   = drive_w[r * kC + 2];
    const float bias = drive_b[r];
    const float freq  = pp[0 * kR + r];
    const float decay = pp[1 * kR + r];
    const float thr   = pp[2 * kR + r];
    const float thrE  = pp[3 * kR + r];
    const float expScale = kAlpha * kLog2e;

    long long b = blockIdx.x;
    issue_sample_loads(traces, b, raw, lane);   // prologue prefetch

    while (b < totalB) {
        // wait for THIS wave's async loads (no barrier; wave-private buffer)
        asm volatile("s_waitcnt vmcnt(0)" ::: "memory");
        sched_fence();

        // ---- pool: window sums + wave max-abs; sp[t*4+c] = window sum ----
        const float4* raw4 = reinterpret_cast<const float4*>(raw);
        float m = 0.0f;
        #pragma unroll
        for (int j = 0; j < kLoads; ++j) {
            float4 v = raw4[j * 64 + lane];           // ds_read_b128
            float s = (v.x + v.y) + (v.z + v.w);
            s += __shfl_xor(s, 1, 64);
            s += __shfl_xor(s, 2, 64);                // window sum in quad
            m = fmaxf(m, fabsf(s));
            if ((lane & 3) == 0) {
                int w = j * 16 + (lane >> 2);         // w = c*128 + t
                sp[(w & 127) * 4 + (w >> 7)] = s;
            }
        }
        #pragma unroll
        for (int off = 32; off >= 4; off >>= 1)       // quads already uniform
            m = fmaxf(m, __shfl_xor(m, off, 64));

        const float inv = fast_rcp(fmaxf(m * (1.0f / 16.0f), 1.0f)) * (1.0f / 16.0f);
        const float v0 = w0 * inv, v1 = w1 * inv, v2 = w2 * inv;

        // raw[] fully consumed -> safe to overwrite: issue next sample's loads
        asm volatile("s_waitcnt lgkmcnt(0)" ::: "memory");
        sched_fence();
        const long long bn = b + gridDim.x;
        if (bn < totalB)
            issue_sample_loads(traces, bn, raw, lane);
        sched_fence();

        // ---- 128-step resonator scan (broadcast ds_read_b128 per step) ----
        const float4* pt = reinterpret_cast<const float4*>(sp);
        float state = 0.0f, vel = 0.0f, acc = 0.0f;
        #pragma unroll 8
        for (int t = 0; t < kTB; ++t) {
            float4 p = pt[t];
            float cur = fmaf(p.x, v0, bias);
            cur = fmaf(p.y, v1, cur);
            cur = fmaf(p.z, v2, cur);
            vel = fmaf(decay, vel, cur);
            vel = fmaf(-freq, state, vel);
            state = fmaf(freq, vel, state);
            float e = fast_exp2(fmaf(-expScale, state, thrE));
            float spike = fast_rcp(1.0f + e);
            state = fmaf(-spike, thr, state);
            acc += spike;
        }

        out[b * kR + r] = acc * (1.0f / kTB);
        b = bn;
    }
}

extern "C" void kernel_launch(void* const* d_in, const int* in_sizes, int n_in,
                              void* d_out, int out_size, void* d_ws, size_t ws_size,
                              hipStream_t stream)
{
    const float* traces   = (const float*)d_in[0];
    const float* drive_w  = (const float*)d_in[1];
    const float* drive_b  = (const float*)d_in[2];
    const float* freq_raw = (const float*)d_in[3];
    const float* q_raw    = (const float*)d_in[4];
    const float* thr_raw  = (const float*)d_in[5];
    float* out = (float*)d_out;
    float* pp  = (float*)d_ws;

    const int totalB = in_sizes[0] / (kC * kTIn);   // 8192
    const int grid = (totalB < 1536) ? totalB : 1536;  // 6 blocks/CU resident

    param_kernel<<<1, 64, 0, stream>>>(freq_raw, q_raw, thr_raw, pp);
    fused_encoder_kernel<<<grid, 64, 0, stream>>>(traces, drive_w, drive_b, pp, out, totalB);
}

// Round 6
// 53.379 us; speedup vs baseline: 1.2959x; 1.2959x over previous
//
#include <hip/hip_runtime.h>
#include <math.h>

// Problem constants (from reference)
constexpr int kC   = 3;
constexpr int kTIn = 2048;
constexpr int kR   = 64;
constexpr int kTB  = 128;
constexpr float kAlpha = 10.0f;
constexpr float kLog2e = 1.44269504088896f;

constexpr int kK          = 4;                  // samples per wave
constexpr int kF4Sample   = kC * kTIn / 4;      // 1536 float4 per sample
constexpr int kJ          = 6;                  // float4 loads per lane per chunk
constexpr int kChunkF4    = kJ * 64;            // 384 float4 per chunk (4 chunks/sample)

#ifndef __has_builtin
#define __has_builtin(x) 0
#endif

static __device__ __forceinline__ float fast_rcp(float x) {
#if __has_builtin(__builtin_amdgcn_rcpf)
    return __builtin_amdgcn_rcpf(x);
#else
    return 1.0f / x;
#endif
}

static __device__ __forceinline__ float fast_exp2(float x) {
#if __has_builtin(__builtin_amdgcn_exp2f)
    return __builtin_amdgcn_exp2f(x);
#else
    return __builtin_exp2f(x);
#endif
}

static __device__ __forceinline__ void sched_fence() {
#if __has_builtin(__builtin_amdgcn_sched_barrier)
    __builtin_amdgcn_sched_barrier(0);
#endif
}

// ---------------------------------------------------------------------------
// Per-resonator transcendental params, once (libm accuracy).
// ws: [4][kR] = freq, decay, thr, thrE (= ALPHA*log2e*thr)
// ---------------------------------------------------------------------------
__global__ void param_kernel(const float* __restrict__ freq_raw,
                             const float* __restrict__ q_raw,
                             const float* __restrict__ thr_raw,
                             float* __restrict__ pp)
{
    const int r = threadIdx.x;
    if (r >= kR) return;
    const float freq  = 0.03f + 0.17f / (1.0f + expf(-freq_raw[r]));
    const float qf    = 1.5f + log1pf(expf(q_raw[r]));
    const float decay = expf(-1.0f / qf);
    const float thr   = 0.35f + 0.75f / (1.0f + expf(-thr_raw[r]));
    pp[0 * kR + r] = freq;
    pp[1 * kR + r] = decay;
    pp[2 * kR + r] = thr;
    pp[3 * kR + r] = thr * (kAlpha * kLog2e);
}

// ---------------------------------------------------------------------------
// Per-wave chunked pipeline, no barriers. Each wave owns kK samples.
// Sample k+1's 24 loads issue in 4 chunks of 6 float4 (24 VGPR in flight),
// interleaved at the quarter-points of sample k's 128-step scan; consumed
// (pool + max) into the double-buffered sp just before the next chunk issues.
// Register-level vmcnt tracking => no false serialization.
// ---------------------------------------------------------------------------
__global__ __launch_bounds__(256, 2)
void fused_encoder_kernel(const float* __restrict__ traces,
                          const float* __restrict__ drive_w,
                          const float* __restrict__ drive_b,
                          const float* __restrict__ pp,
                          float* __restrict__ out)
{
    __shared__ float sp_all[4][2][kTB * 4];   // [wave][buf][t*4+c] = 16 KB
    const int tid  = threadIdx.x;
    const int wave = tid >> 6;
    const int lane = tid & 63;
    float (*sp)[kTB * 4] = sp_all[wave];
    const int gw = blockIdx.x * 4 + wave;
    const long long base = (long long)gw * kK;   // first sample of this wave

    // per-lane resonator params (lane == resonator)
    const int r = lane;
    const float w0   = drive_w[r * kC + 0];
    const float w1   = drive_w[r * kC + 1];
    const float w2   = drive_w[r * kC + 2];
    const float bias = drive_b[r];
    const float freq  = pp[0 * kR + r];
    const float decay = pp[1 * kR + r];
    const float thr   = pp[2 * kR + r];
    const float thrE  = pp[3 * kR + r];
    const float expScale = kAlpha * kLog2e;

    const float4* tr4 = reinterpret_cast<const float4*>(traces);

    float4 R[kJ];        // one chunk in flight (24 VGPR)
    float  m = 0.0f;     // running window-sum max of the sample being pooled
    float  inv;          // normalization of the sample being scanned

    auto issue = [&](long long b, int q) {
        const float4* src = tr4 + b * kF4Sample + q * kChunkF4 + lane;
        #pragma unroll
        for (int j = 0; j < kJ; ++j) R[j] = src[j * 64];
    };
    // pool chunk q into sp[buf]: window w = q*96 + j*16 + (lane>>2)
    auto consume = [&](int q, int buf) {
        #pragma unroll
        for (int j = 0; j < kJ; ++j) {
            float4 v = R[j];
            float s = (v.x + v.y) + (v.z + v.w);
            s += __shfl_xor(s, 1, 64);
            s += __shfl_xor(s, 2, 64);              // full window sum in quad
            m = fmaxf(m, fabsf(s));
            if ((lane & 3) == 0) {
                int w = q * 96 + j * 16 + (lane >> 2);   // w = c*128 + t
                sp[buf][(w & 127) * 4 + (w >> 7)] = s;   // 2-way alias: free
            }
        }
    };
    auto finish_max = [&]() {
        #pragma unroll
        for (int off = 4; off <= 32; off <<= 1)     // quads already uniform
            m = fmaxf(m, __shfl_xor(m, off, 64));
        inv = fast_rcp(fmaxf(m * (1.0f / 16.0f), 1.0f)) * (1.0f / 16.0f);
        m = 0.0f;
    };

    // ---- prologue: pool sample base+0 into buffer 0 ----
    for (int q = 0; q < 4; ++q) { issue(base, q); consume(q, 0); }
    finish_max();

    for (int k = 0; k < kK; ++k) {
        const int cur = k & 1, nxt = cur ^ 1;
        const bool hn = (k + 1 < kK);
        const float v0 = w0 * inv, v1 = w1 * inv, v2 = w2 * inv;
        const float4* pt = reinterpret_cast<const float4*>(sp[cur]);

        float state = 0.0f, vel = 0.0f, acc = 0.0f;
        for (int seg = 0; seg < 4; ++seg) {
            if (hn) {
                if (seg > 0) consume(seg - 1, nxt);   // chunk seg-1 has landed
                issue(base + k + 1, seg);             // next chunk in flight
                sched_fence();                        // pin issue before scan
            }
            #pragma unroll
            for (int tt = 0; tt < 32; ++tt) {
                float4 p = pt[seg * 32 + tt];         // broadcast ds_read_b128
                float cur_ = fmaf(p.x, v0, bias);
                cur_ = fmaf(p.y, v1, cur_);
                cur_ = fmaf(p.z, v2, cur_);
                vel = fmaf(decay, vel, cur_);
                vel = fmaf(-freq, state, vel);
                state = fmaf(freq, vel, state);
                float e = fast_exp2(fmaf(-expScale, state, thrE));
                float spike = fast_rcp(1.0f + e);
                state = fmaf(-spike, thr, state);
                acc += spike;
            }
        }

        out[(base + k) * kR + r] = acc * (1.0f / kTB);
        if (hn) {
            consume(3, nxt);
            finish_max();
        }
    }
}

extern "C" void kernel_launch(void* const* d_in, const int* in_sizes, int n_in,
                              void* d_out, int out_size, void* d_ws, size_t ws_size,
                              hipStream_t stream)
{
    const float* traces   = (const float*)d_in[0];
    const float* drive_w  = (const float*)d_in[1];
    const float* drive_b  = (const float*)d_in[2];
    const float* freq_raw = (const float*)d_in[3];
    const float* q_raw    = (const float*)d_in[4];
    const float* thr_raw  = (const float*)d_in[5];
    float* out = (float*)d_out;
    float* pp  = (float*)d_ws;

    const int totalB = in_sizes[0] / (kC * kTIn);   // 8192
    const int W    = totalB / kK;                   // 2048 waves
    const int grid = W / 4;                         // 512 blocks

    param_kernel<<<1, 64, 0, stream>>>(freq_raw, q_raw, thr_raw, pp);
    fused_encoder_kernel<<<grid, 256, 0, stream>>>(traces, drive_w, drive_b, pp, out);
}

// Round 7
// 44.345 us; speedup vs baseline: 1.5598x; 1.2037x over previous
//
#include <hip/hip_runtime.h>
#include <math.h>

// Problem constants (from reference)
constexpr int kC   = 3;
constexpr int kTIn = 2048;
constexpr int kR   = 64;
constexpr int kTB  = 128;
constexpr float kAlpha = 10.0f;
constexpr float kLog2e = 1.44269504088896f;

constexpr int kK   = 4;              // samples per block
constexpr int kF4  = kC * kTIn / 4;  // 1536 float4 per sample

#ifndef __has_builtin
#define __has_builtin(x) 0
#endif

static __device__ __forceinline__ float fast_rcp(float x) {
#if __has_builtin(__builtin_amdgcn_rcpf)
    return __builtin_amdgcn_rcpf(x);
#else
    return 1.0f / x;
#endif
}

static __device__ __forceinline__ float fast_exp2(float x) {
#if __has_builtin(__builtin_amdgcn_exp2f)
    return __builtin_amdgcn_exp2f(x);
#else
    return __builtin_exp2f(x);
#endif
}

// ---------------------------------------------------------------------------
// Per-resonator transcendental params, once (libm accuracy).
// ws: [4][kR] = freq, decay, thr, thrE (= ALPHA*log2e*thr)
// ---------------------------------------------------------------------------
__global__ void param_kernel(const float* __restrict__ freq_raw,
                             const float* __restrict__ q_raw,
                             const float* __restrict__ thr_raw,
                             float* __restrict__ pp)
{
    const int r = threadIdx.x;
    if (r >= kR) return;
    const float freq  = 0.03f + 0.17f / (1.0f + expf(-freq_raw[r]));
    const float qf    = 1.5f + log1pf(expf(q_raw[r]));
    const float decay = expf(-1.0f / qf);
    const float thr   = 0.35f + 0.75f / (1.0f + expf(-thr_raw[r]));
    pp[0 * kR + r] = freq;
    pp[1 * kR + r] = decay;
    pp[2 * kR + r] = thr;
    pp[3 * kR + r] = thr * (kAlpha * kLog2e);
}

// ---------------------------------------------------------------------------
// Wave-specialized producer/consumer block. 4 waves, K=4 samples, fully
// resident grid (2048 blocks = 8/CU = 32 waves/CU).
//   helpers (3 waves): load+pool sample k+1 -> sp[nxt], wave-max -> red[nxt]
//   scanner (1 wave, = blockIdx&3 to spread across SIMDs): scan sp[cur]
//   one __syncthreads per iteration = handoff.
// Scan (~4.3us) hides under the iteration's memory drain (~7.8us/CU).
// ---------------------------------------------------------------------------
__global__ __launch_bounds__(256, 8)
void fused_encoder_kernel(const float* __restrict__ traces,
                          const float* __restrict__ drive_w,
                          const float* __restrict__ drive_b,
                          const float* __restrict__ pp,
                          float* __restrict__ out)
{
    __shared__ float sp[2][kTB * 4];   // [buf][t*4+c], 4 KB
    __shared__ float red[2][3];        // per-helper-wave maxes

    const int tid  = threadIdx.x;
    const int wave = tid >> 6;
    const int lane = tid & 63;
    const int scanWave = blockIdx.x & 3;
    const long long base = (long long)blockIdx.x * kK;
    const float4* tr4 = reinterpret_cast<const float4*>(traces);

    if (wave != scanWave) {
        // ================= helper: load + pool + max =================
        const int h = wave - (wave > scanWave ? 1 : 0);   // 0..2

        auto pool = [&](long long b, int buf) {
            const float4* src = tr4 + b * kF4 + (h * 8) * 64 + lane;
            float mloc = 0.0f;
            #pragma unroll
            for (int j = 0; j < 8; ++j) {
                float4 v = src[j * 64];                   // coalesced 1 KB/inst
                float s = (v.x + v.y) + (v.z + v.w);
                s += __shfl_xor(s, 1, 64);
                s += __shfl_xor(s, 2, 64);                // window sum in quad
                mloc = fmaxf(mloc, fabsf(s));
                if ((lane & 3) == 0) {
                    int w = (h * 8 + j) * 16 + (lane >> 2);   // w = c*128 + t
                    sp[buf][(w & 127) * 4 + (w >> 7)] = s;
                }
            }
            #pragma unroll
            for (int off = 4; off <= 32; off <<= 1)       // quads already uniform
                mloc = fmaxf(mloc, __shfl_xor(mloc, off, 64));
            if (lane == 0) red[buf][h] = mloc;
        };

        pool(base, 0);                 // prologue: sample 0 -> buf 0
        __syncthreads();
        for (int k = 0; k < kK; ++k) {
            if (k + 1 < kK) pool(base + k + 1, (k + 1) & 1);
            __syncthreads();
        }
    } else {
        // ================= scanner: params + 128-step scan =================
        const int r = lane;
        const float w0   = drive_w[r * kC + 0];
        const float w1   = drive_w[r * kC + 1];
        const float w2   = drive_w[r * kC + 2];
        const float bias = drive_b[r];
        const float freq  = pp[0 * kR + r];
        const float decay = pp[1 * kR + r];
        const float thr   = pp[2 * kR + r];
        const float thrE  = pp[3 * kR + r];
        const float expScale = kAlpha * kLog2e;

        __syncthreads();
        for (int k = 0; k < kK; ++k) {
            const int cur = k & 1;
            const float mm = fmaxf(fmaxf(red[cur][0], red[cur][1]), red[cur][2]);
            const float inv = fast_rcp(fmaxf(mm * (1.0f / 16.0f), 1.0f)) * (1.0f / 16.0f);
            const float v0 = w0 * inv, v1 = w1 * inv, v2 = w2 * inv;
            const float4* pt = reinterpret_cast<const float4*>(sp[cur]);

            __builtin_amdgcn_s_setprio(1);
            float state = 0.0f, vel = 0.0f, acc = 0.0f;
            #pragma unroll 8
            for (int t = 0; t < kTB; ++t) {
                float4 p = pt[t];                     // broadcast ds_read_b128
                float cur_ = fmaf(p.x, v0, bias);
                cur_ = fmaf(p.y, v1, cur_);
                cur_ = fmaf(p.z, v2, cur_);
                vel = fmaf(decay, vel, cur_);
                vel = fmaf(-freq, state, vel);
                state = fmaf(freq, vel, state);
                float e = fast_exp2(fmaf(-expScale, state, thrE));
                float spike = fast_rcp(1.0f + e);
                state = fmaf(-spike, thr, state);
                acc += spike;
            }
            __builtin_amdgcn_s_setprio(0);

            out[(base + k) * kR + r] = acc * (1.0f / kTB);
            __syncthreads();
        }
    }
}

extern "C" void kernel_launch(void* const* d_in, const int* in_sizes, int n_in,
                              void* d_out, int out_size, void* d_ws, size_t ws_size,
                              hipStream_t stream)
{
    const float* traces   = (const float*)d_in[0];
    const float* drive_w  = (const float*)d_in[1];
    const float* drive_b  = (const float*)d_in[2];
    const float* freq_raw = (const float*)d_in[3];
    const float* q_raw    = (const float*)d_in[4];
    const float* thr_raw  = (const float*)d_in[5];
    float* out = (float*)d_out;
    float* pp  = (float*)d_ws;

    const int totalB = in_sizes[0] / (kC * kTIn);   // 8192
    const int grid = totalB / kK;                   // 2048 blocks, fully resident

    param_kernel<<<1, 64, 0, stream>>>(freq_raw, q_raw, thr_raw, pp);
    fused_encoder_kernel<<<grid, 256, 0, stream>>>(traces, drive_w, drive_b, pp, out);
}